// Round 4
// baseline (36.114 us; speedup 1.0000x reference)
//
#include <hip/hip_runtime.h>
#include <hip/hip_bf16.h>

#define D 128

// ---------------------------------------------------------------------------
// Fused kernel: prologue computes b_w = b_alpha^T W_alpha and
// c = (a_alpha^T W_alpha) . X[0] redundantly per block (W_alpha is 64 KB,
// L2-resident; aggregate cost ~4 us of L2 BW, overlapped). Main loop streams
// X once: each 32-lane subgroup owns 2 rows/iter with explicit next-tile
// prefetch so HBM latency hides under dot/shfl/exp compute.
// ---------------------------------------------------------------------------
__global__ __launch_bounds__(256, 8) void fused_main_kernel(
    const float* __restrict__ X,
    const float* __restrict__ W_alpha,
    const float* __restrict__ a_alpha,
    const float* __restrict__ b_alpha,
    float* __restrict__ partial_wsum,    // [gridDim.x][D]
    float* __restrict__ partial_alpha,   // [gridDim.x]
    int nrows)
{
    const int t = threadIdx.x;

    // ---------------- prologue: b_w and c (every block) ----------------
    __shared__ float aal[D], bal[D];
    __shared__ float raw2[2][D], rbw2[2][D];
    __shared__ float bw_sh[D];
    __shared__ float csum[2];

    if (t < D) { aal[t] = a_alpha[t]; bal[t] = b_alpha[t]; }
    __syncthreads();

    {
        const int kk = t & 127;
        const int gg = t >> 7;            // 0..1 -> rows gg*64 .. gg*64+63
        float aw = 0.f, bw = 0.f;
        #pragma unroll 8
        for (int i = gg * 64; i < gg * 64 + 64; ++i) {
            const float w = W_alpha[i * D + kk];   // coalesced across kk
            aw = fmaf(aal[i], w, aw);
            bw = fmaf(bal[i], w, bw);
        }
        raw2[gg][kk] = aw;
        rbw2[gg][kk] = bw;
    }
    __syncthreads();

    if (t < D) {
        const float A = raw2[0][t] + raw2[1][t];
        bw_sh[t]      = rbw2[0][t] + rbw2[1][t];
        float part = A * X[t];
        #pragma unroll
        for (int m = 32; m >= 1; m >>= 1) part += __shfl_xor(part, m, 64);
        if ((t & 63) == 0) csum[t >> 6] = part;
    }
    __syncthreads();

    const float c = csum[0] + csum[1];

    // ---------------- main streaming pass ----------------
    const int col4 = t & 31;   // which float4 of the row
    const int rg   = t >> 5;   // row-group 0..7 within the block

    const float4 bwv = make_float4(bw_sh[col4 * 4 + 0], bw_sh[col4 * 4 + 1],
                                   bw_sh[col4 * 4 + 2], bw_sh[col4 * 4 + 3]);

    float a0 = 0.f, a1 = 0.f, a2 = 0.f, a3 = 0.f;
    float aacc = 0.f;

    const int ntiles = (nrows + 15) >> 4;   // 16 rows per block-iteration
    const float4* __restrict__ X4 = reinterpret_cast<const float4*>(X);
    const float4 fz = make_float4(0.f, 0.f, 0.f, 0.f);

    int tile = blockIdx.x;
    float4 x0 = fz, x1 = fz;
    bool v0 = false, v1 = false;
    if (tile < ntiles) {
        const int r0 = tile * 16 + rg * 2;
        v0 = r0 < nrows; v1 = (r0 + 1) < nrows;
        if (v0) x0 = X4[(size_t)r0 * 32 + col4];
        if (v1) x1 = X4[(size_t)(r0 + 1) * 32 + col4];
    }

    while (tile < ntiles) {
        const int ntile = tile + gridDim.x;
        float4 n0 = fz, n1 = fz;
        bool w0 = false, w1 = false;
        if (ntile < ntiles) {
            const int r0 = ntile * 16 + rg * 2;
            w0 = r0 < nrows; w1 = (r0 + 1) < nrows;
            if (w0) n0 = X4[(size_t)r0 * 32 + col4];      // prefetch next tile
            if (w1) n1 = X4[(size_t)(r0 + 1) * 32 + col4];
        }

        float d0 = fmaf(x0.x, bwv.x, fmaf(x0.y, bwv.y, fmaf(x0.z, bwv.z, x0.w * bwv.w)));
        float d1 = fmaf(x1.x, bwv.x, fmaf(x1.y, bwv.y, fmaf(x1.z, bwv.z, x1.w * bwv.w)));
        #pragma unroll
        for (int m = 16; m >= 1; m >>= 1) {
            d0 += __shfl_xor(d0, m, 64);
            d1 += __shfl_xor(d1, m, 64);
        }
        const float al0 = v0 ? __expf(d0 + c) : 0.f;
        const float al1 = v1 ? __expf(d1 + c) : 0.f;
        if (col4 == 0) aacc += al0 + al1;
        a0 = fmaf(al0, x0.x, fmaf(al1, x1.x, a0));
        a1 = fmaf(al0, x0.y, fmaf(al1, x1.y, a1));
        a2 = fmaf(al0, x0.z, fmaf(al1, x1.z, a2));
        a3 = fmaf(al0, x0.w, fmaf(al1, x1.w, a3));

        x0 = n0; x1 = n1; v0 = w0; v1 = w1;
        tile = ntile;
    }

    // -------- block reduction (8 row-groups -> one 128-vector) --------
    __shared__ float red[8][32][4];   // 4 KB
    __shared__ float reda[8];
    red[rg][col4][0] = a0;
    red[rg][col4][1] = a1;
    red[rg][col4][2] = a2;
    red[rg][col4][3] = a3;
    if (col4 == 0) reda[rg] = aacc;
    __syncthreads();

    if (t < D) {
        double s = 0.0;
        #pragma unroll
        for (int r = 0; r < 8; ++r) s += (double)red[r][t >> 2][t & 3];
        partial_wsum[(size_t)blockIdx.x * D + t] = (float)s;
    }
    if (t == 0) {
        double s = 0.0;
        #pragma unroll
        for (int r = 0; r < 8; ++r) s += (double)reda[r];
        partial_alpha[blockIdx.x] = (float)s;
    }
}

// ---------------------------------------------------------------------------
// Kernel 2 (NB2 blocks, 512 threads): tree-reduce block partials.
// Block b sums rows {b + NB2*j} -> mid[b][D] (double) + mida[b].
// ---------------------------------------------------------------------------
__global__ __launch_bounds__(512) void reduce1_kernel(
    const float* __restrict__ partial_wsum,
    const float* __restrict__ partial_alpha,
    double* __restrict__ mid,     // [NB2][D]
    double* __restrict__ mida,    // [NB2]
    int NB, int NB2)
{
    const int b  = blockIdx.x;
    const int t  = threadIdx.x;
    const int k  = t & 127;
    const int rs = t >> 7;        // 0..3
    const int nper = NB / NB2;

    double s = 0.0;
    for (int j = rs; j < nper; j += 4)
        s += (double)partial_wsum[(size_t)(b + NB2 * j) * D + k];  // coalesced
    __shared__ double red[4][D];  // 4 KB
    red[rs][k] = s;

    __shared__ double reda[64];
    if (t < nper && t < 64) {
        double sa = 0.0;
        for (int j = t; j < nper; j += 64) sa += (double)partial_alpha[b + NB2 * j];
        reda[t] = sa;
    }
    __syncthreads();

    if (t < D)
        mid[(size_t)b * D + t] = red[0][t] + red[1][t] + red[2][t] + red[3][t];
    if (t == 0) {
        double sa = 0.0;
        const int lim = nper < 64 ? nper : 64;
        for (int i = 0; i < lim; ++i) sa += reda[i];
        mida[b] = sa;
    }
}

// ---------------------------------------------------------------------------
// Kernel 3 (1 block, 1024 threads): final reduce, normalize, @ W_sum.
// ---------------------------------------------------------------------------
__global__ __launch_bounds__(1024) void final_kernel(
    const double* __restrict__ mid,
    const double* __restrict__ mida,
    const float* __restrict__ W_sum,
    float* __restrict__ out,
    int NB2)
{
    const int t = threadIdx.x;
    const int k = t & 127;
    const int g = t >> 7;     // 0..7

    double ws = 0.0;
    for (int j = g; j < NB2; j += 8)
        ws += mid[(size_t)j * D + k];   // coalesced across k
    __shared__ double red[8][D];    // 8 KB
    red[g][k] = ws;

    __shared__ double reda[64];
    if (t < NB2) reda[t] = mida[t];
    __syncthreads();
    __shared__ double asum_sh;
    if (t == 0) {
        double a = 0.0;
        for (int i = 0; i < NB2; ++i) a += reda[i];
        asum_sh = a;
    }
    __syncthreads();

    __shared__ float s_sh[D];
    if (t < D) {
        double s = 0.0;
        #pragma unroll
        for (int r = 0; r < 8; ++r) s += red[r][t];
        s_sh[t] = (float)(s / asum_sh);
    }
    __syncthreads();

    // out[j] = sum_k s[k] * W_sum[k][j], split over the 8 groups
    float o = 0.f;
    #pragma unroll
    for (int kk = g * 16; kk < g * 16 + 16; ++kk)
        o = fmaf(s_sh[kk], W_sum[kk * D + k], o);   // coalesced across k
    __shared__ float rout[8][D];    // 4 KB
    rout[g][k] = o;
    __syncthreads();
    if (t < D) {
        float s = 0.f;
        #pragma unroll
        for (int r = 0; r < 8; ++r) s += rout[r][t];
        out[t] = s;
    }
}

// ---------------------------------------------------------------------------
extern "C" void kernel_launch(void* const* d_in, const int* in_sizes, int n_in,
                              void* d_out, int out_size, void* d_ws, size_t ws_size,
                              hipStream_t stream) {
    const float* X       = (const float*)d_in[0];
    const float* W_sum   = (const float*)d_in[1];
    const float* W_alpha = (const float*)d_in[2];
    const float* a_alpha = (const float*)d_in[3];
    const float* b_alpha = (const float*)d_in[4];
    float* out = (float*)d_out;

    const int nrows = in_sizes[0] / D;   // 200000
    const int NB2 = 64;

    int NB = 2048;
    auto need = [&](int nb) {
        return (size_t)nb * D * sizeof(float)        // partial_wsum
             + (size_t)nb * sizeof(float)            // partial_alpha
             + 256
             + (size_t)NB2 * D * sizeof(double)      // mid
             + (size_t)NB2 * sizeof(double);         // mida
    };
    while (NB > NB2 && need(NB) > ws_size) NB >>= 1;

    char* ws = (char*)d_ws;
    float*  partial_wsum  = (float*)ws;
    float*  partial_alpha = (float*)(ws + (size_t)NB * D * sizeof(float));
    size_t off = (size_t)NB * (D + 1) * sizeof(float);
    off = (off + 255) & ~(size_t)255;
    double* mid  = (double*)(ws + off);
    double* mida = mid + (size_t)NB2 * D;

    fused_main_kernel<<<NB, 256, 0, stream>>>(X, W_alpha, a_alpha, b_alpha,
                                              partial_wsum, partial_alpha, nrows);
    reduce1_kernel<<<NB2, 512, 0, stream>>>(partial_wsum, partial_alpha,
                                            mid, mida, NB, NB2);
    final_kernel<<<1, 1024, 0, stream>>>(mid, mida, W_sum, out, NB2);
}